// Round 8
// baseline (1153.055 us; speedup 1.0000x reference)
//
#include <hip/hip_runtime.h>
#include <cstdint>
#include <cstddef>

#define NNODES 100000
#define NEDGES 3200000
#define NF 128

// coarse buckets: 256 nodes each
#define S1_SHIFT 8
#define S1_BW 256
#define S1_NB ((NNODES + S1_BW - 1) / S1_BW)  // 391
#define S1_CH 4096
#define S1_T 256
#define S1_GRID ((NEDGES + S1_CH - 1) / S1_CH)  // 782

typedef __attribute__((ext_vector_type(8))) short short8v;
typedef __attribute__((ext_vector_type(4))) float float4v;
typedef __attribute__((ext_vector_type(2))) float float2v;

static __device__ __forceinline__ uint16_t f2bf(float f) {
  uint32_t u = __float_as_uint(f);
  return (uint16_t)((u + 0x7fffu + ((u >> 16) & 1u)) >> 16);  // RNE
}
static __device__ __forceinline__ float bflo(uint32_t u) { return __uint_as_float(u << 16); }
static __device__ __forceinline__ float bfhi(uint32_t u) { return __uint_as_float(u & 0xffff0000u); }

// ============ bucket histogram (LDS-privatized) ============
__global__ __launch_bounds__(256) void k_bhist(const int* __restrict__ recv,
                                               int* __restrict__ bcount) {
  __shared__ int h[S1_NB];
  for (int i = threadIdx.x; i < S1_NB; i += 256) h[i] = 0;
  __syncthreads();
  const int stride = 256 * 256;
  for (int i = blockIdx.x * 256 + threadIdx.x; i < NEDGES; i += stride)
    atomicAdd(&h[recv[i] >> S1_SHIFT], 1);
  __syncthreads();
  for (int i = threadIdx.x; i < S1_NB; i += 256) {
    int v = h[i];
    if (v) atomicAdd(&bcount[i], v);
  }
}

// ============ bucket exclusive scan (single block, 391 <= 512) ============
__global__ __launch_bounds__(512) void k_bscan(const int* __restrict__ bcount,
                                               int* __restrict__ boffs,
                                               int* __restrict__ bcursor) {
  __shared__ int sd[512];
  int t = threadIdx.x;
  int v = (t < S1_NB) ? bcount[t] : 0;
  sd[t] = v;
  __syncthreads();
  for (int off = 1; off < 512; off <<= 1) {
    int x = (t >= off) ? sd[t - off] : 0;
    __syncthreads();
    sd[t] += x;
    __syncthreads();
  }
  if (t < S1_NB) {
    int o = sd[t] - v;
    boffs[t] = o;
    bcursor[t] = o;
  }
  if (t == S1_NB - 1) boffs[S1_NB] = sd[t];
}

// ============ pass 1: block-local bucket binning, direct run store ============
__global__ __launch_bounds__(S1_T) void k_sort1(const int* __restrict__ send,
                                                const int* __restrict__ recv,
                                                const float* __restrict__ ev,
                                                int* __restrict__ bcursor,
                                                uint2* __restrict__ buf) {
  __shared__ uint2 sbuf[S1_CH];       // 32 KB staged edges
  __shared__ uint16_t sb_b[S1_CH];    // 8 KB bucket id per edge
  __shared__ int h[S1_NB];            // hist, then insert-cursor
  __shared__ int gb[S1_NB];           // global run base per bucket
  const int t = threadIdx.x;
  const int base = blockIdx.x * S1_CH;
  const int nb = min(S1_CH, NEDGES - base);
  for (int i = t; i < S1_NB; i += S1_T) h[i] = 0;
  __syncthreads();
  for (int i = t; i < nb; i += S1_T) {
    int s = send[base + i];
    int r = recv[base + i];
    float w = ev[base + i];
    int b = r >> S1_SHIFT;
    sbuf[i] = make_uint2((uint32_t)s | ((uint32_t)(r & (S1_BW - 1)) << 17), __float_as_uint(w));
    sb_b[i] = (uint16_t)b;
    atomicAdd(&h[b], 1);
  }
  __syncthreads();
  for (int i = t; i < S1_NB; i += S1_T) {
    int v = h[i];
    if (v) gb[i] = atomicAdd(&bcursor[i], v);
    h[i] = 0;  // reuse as cursor
  }
  __syncthreads();
  for (int i = t; i < nb; i += S1_T) {
    int b = sb_b[i];
    int rk = atomicAdd(&h[b], 1);
    buf[gb[b] + rk] = sbuf[i];
  }
}

// ============ pass 2: per-bucket sort to node granularity -> 4B-record CSR ============
// record: evbf15(sign-less bf16 of edge_val) << 17 | sender(17 bits)
__global__ __launch_bounds__(256) void k_pass2(const uint2* __restrict__ buf,
                                               const int* __restrict__ boffs,
                                               int* __restrict__ offs,
                                               int* __restrict__ counts,
                                               uint32_t* __restrict__ csr4) {
  __shared__ int hcnt[S1_BW], hoff2[S1_BW], sd[S1_BW];
  const int b = blockIdx.x, t = threadIdx.x;
  const int bstart = boffs[b], bend = boffs[b + 1];
  const int nb = bend - bstart;
  hcnt[t] = 0;
  __syncthreads();
  for (int i = t; i < nb; i += 256) atomicAdd(&hcnt[buf[bstart + i].x >> 17], 1);
  __syncthreads();
  int v = hcnt[t];
  sd[t] = v;
  __syncthreads();
  for (int off = 1; off < 256; off <<= 1) {
    int x = (t >= off) ? sd[t - off] : 0;
    __syncthreads();
    sd[t] += x;
    __syncthreads();
  }
  int excl = sd[t] - v;
  hoff2[t] = excl;
  int node = b * S1_BW + t;
  if (node < NNODES) {
    offs[node] = bstart + excl;
    counts[node] = v;
  }
  hcnt[t] = 0;
  __syncthreads();
  for (int i = t; i < nb; i += 256) {
    uint2 e = buf[bstart + i];
    uint32_t rl = e.x >> 17;
    int pos = bstart + hoff2[rl] + atomicAdd(&hcnt[rl], 1);
    uint32_t evb = (uint32_t)(f2bf(__uint_as_float(e.y)) & 0x7FFFu);
    csr4[pos] = (evb << 17) | (e.x & 0x1FFFFu);
  }
}

// ============ W -> bf16, transposed [n][k] ============
__global__ __launch_bounds__(256) void k_wprep(const float* __restrict__ W1,
                                               const float* __restrict__ W2,
                                               uint16_t* __restrict__ wT) {
  const float* W = blockIdx.x ? W2 : W1;
  uint16_t* o = wT + blockIdx.x * 16384;
  for (int i = threadIdx.x; i < 16384; i += 256) {
    int k = i >> 7, n = i & 127;
    o[n * 128 + k] = f2bf(W[i]);
  }
}

// ============ MFMA bf16 GEMM: Y[N,128](bf16) = X[N,128] @ W ============
template <bool XF32>
__global__ __launch_bounds__(256) void k_gemm(const void* __restrict__ Xv,
                                              const uint16_t* __restrict__ wT,
                                              uint16_t* __restrict__ Y) {
  __shared__ uint16_t sX[64 * 128];
  __shared__ uint16_t sWT[128 * 128];  // [n][k], swizzled 16B chunks
  const int t = threadIdx.x;
  const int r0 = blockIdx.x * 64;
  {
    const uint4* src = (const uint4*)wT;
    uint4* dst = (uint4*)sWT;
#pragma unroll
    for (int j = 0; j < 8; ++j) {
      int i = j * 256 + t;
      int row = i >> 4;
      dst[(i & ~15) | ((i & 15) ^ (row & 7))] = src[i];
    }
  }
  if (XF32) {
    const float* X = (const float*)Xv;
    int r = t >> 2, c0 = (t & 3) * 32;
    int grow = r0 + r;
    if (grow >= NNODES) grow = NNODES - 1;
    const float* xp = X + (size_t)grow * 128 + c0;
    uint4* xdst = (uint4*)sX;
#pragma unroll
    for (int j = 0; j < 4; ++j) {
      float4 f0 = *(const float4*)(xp + j * 8);
      float4 f1 = *(const float4*)(xp + j * 8 + 4);
      uint4 vv;
      vv.x = (uint32_t)f2bf(f0.x) | ((uint32_t)f2bf(f0.y) << 16);
      vv.y = (uint32_t)f2bf(f0.z) | ((uint32_t)f2bf(f0.w) << 16);
      vv.z = (uint32_t)f2bf(f1.x) | ((uint32_t)f2bf(f1.y) << 16);
      vv.w = (uint32_t)f2bf(f1.z) | ((uint32_t)f2bf(f1.w) << 16);
      int kc = (c0 >> 3) + j;
      xdst[r * 16 + (kc ^ (r & 7))] = vv;
    }
  } else {
    const uint4* src = (const uint4*)((const char*)Xv + (size_t)r0 * 256);
    uint4* xdst = (uint4*)sX;
    size_t maxByte = (size_t)NNODES * 256 - (size_t)r0 * 256;
#pragma unroll
    for (int j = 0; j < 4; ++j) {
      int i = j * 256 + t;
      int row = i >> 4;
      uint4 vv = ((size_t)i * 16 < maxByte) ? src[i] : make_uint4(0, 0, 0, 0);
      xdst[(i & ~15) | ((i & 15) ^ (row & 7))] = vv;
    }
  }
  __syncthreads();
  const int l = t & 63, w = t >> 6;
  const int m16 = l & 15, kb = l >> 4;
  const int arow = w * 16 + m16;
  short8v a[4];
#pragma unroll
  for (int ks = 0; ks < 4; ++ks) {
    int elem = (ks * 32 + kb * 8) ^ ((arow & 7) << 3);
    a[ks] = *reinterpret_cast<const short8v*>(&sX[arow * 128 + elem]);
  }
  float4v acc[8] = {};
#pragma unroll
  for (int nt = 0; nt < 8; ++nt) {
    int brow = nt * 16 + m16;
    int bswz = (brow & 7) << 3;
    int bbase = brow * 128;
#pragma unroll
    for (int ks = 0; ks < 4; ++ks) {
      short8v bb = *reinterpret_cast<const short8v*>(&sWT[bbase + ((ks * 32 + kb * 8) ^ bswz)]);
      acc[nt] = __builtin_amdgcn_mfma_f32_16x16x32_bf16(a[ks], bb, acc[nt], 0, 0, 0);
    }
  }
  const int orow0 = r0 + w * 16 + kb * 4;
#pragma unroll
  for (int nt = 0; nt < 8; ++nt) {
    int col = nt * 16 + m16;
#pragma unroll
    for (int q = 0; q < 4; ++q) {
      int grow = orow0 + q;
      if (grow < NNODES) Y[(size_t)grow * 128 + col] = f2bf(acc[nt][q]);
    }
  }
}

// ============ SpMM + bias + relu: XCD feature-sliced ============
// slice = blockIdx & 7 -> one XCD per slice (round-robin dispatch); per-XCD gather
// working set = 100000 x 32 B = 3.2 MB -> L2-resident. Wave = 8 nodes x 8 lanes;
// each 8-lane group owns one node's 16-feature slice (2 feats/lane, no shuffles).
template <bool OUTBF>
__global__ __launch_bounds__(256) void k_spmm(const uint16_t* __restrict__ supp,
                                              const uint32_t* __restrict__ csr4,
                                              const int* __restrict__ offs,
                                              const int* __restrict__ counts,
                                              const float* __restrict__ bias,
                                              void* __restrict__ outp) {
  const int bid = blockIdx.x;
  const int s = bid & 7;         // feature slice / XCD
  const int ng = bid >> 3;       // node group of 32
  const int t = threadIdx.x;
  const int lane = t & 63, w = t >> 6;
  const int nsub = lane >> 3;    // node within wave: 0..7
  const int f = lane & 7;        // feat pair within slice: 2 feats
  const int node = ng * 32 + w * 8 + nsub;
  const int start = offs[node], deg = counts[node];
  const char* tab = (const char*)supp + s * 32 + f * 4;
  const uint32_t* e = csr4 + start;
  float a0 = 0.f, a1 = 0.f;
  int i = 0;
  for (; i + 4 <= deg; i += 4) {
    uint32_t r0 = __builtin_nontemporal_load(&e[i]);
    uint32_t r1 = __builtin_nontemporal_load(&e[i + 1]);
    uint32_t r2 = __builtin_nontemporal_load(&e[i + 2]);
    uint32_t r3 = __builtin_nontemporal_load(&e[i + 3]);
    uint32_t h0 = *(const uint32_t*)(tab + (size_t)(r0 & 0x1FFFFu) * 256);
    uint32_t h1 = *(const uint32_t*)(tab + (size_t)(r1 & 0x1FFFFu) * 256);
    uint32_t h2 = *(const uint32_t*)(tab + (size_t)(r2 & 0x1FFFFu) * 256);
    uint32_t h3 = *(const uint32_t*)(tab + (size_t)(r3 & 0x1FFFFu) * 256);
    float v0 = __uint_as_float((r0 >> 1) & 0x7FFF0000u);
    float v1 = __uint_as_float((r1 >> 1) & 0x7FFF0000u);
    float v2 = __uint_as_float((r2 >> 1) & 0x7FFF0000u);
    float v3 = __uint_as_float((r3 >> 1) & 0x7FFF0000u);
    a0 += v0 * bflo(h0); a1 += v0 * bfhi(h0);
    a0 += v1 * bflo(h1); a1 += v1 * bfhi(h1);
    a0 += v2 * bflo(h2); a1 += v2 * bfhi(h2);
    a0 += v3 * bflo(h3); a1 += v3 * bfhi(h3);
  }
  if (i < deg) {  // predicated tail (<=3 real edges), clamped index, zeroed weight
    const int dm1 = deg - 1;
#pragma unroll
    for (int p = 0; p < 3; ++p) {
      int idx = i + p;
      uint32_t r0 = e[min(idx, dm1)];
      uint32_t h0 = *(const uint32_t*)(tab + (size_t)(r0 & 0x1FFFFu) * 256);
      float v0 = (idx < deg) ? __uint_as_float((r0 >> 1) & 0x7FFF0000u) : 0.f;
      a0 += v0 * bflo(h0);
      a1 += v0 * bfhi(h0);
    }
  }
  const int fb = s * 16 + f * 2;
  float o0 = fmaxf(a0 + bias[fb], 0.f);
  float o1 = fmaxf(a1 + bias[fb + 1], 0.f);
  if (OUTBF) {
    uint32_t pk = (uint32_t)f2bf(o0) | ((uint32_t)f2bf(o1) << 16);
    __builtin_nontemporal_store(pk, &((uint32_t*)outp)[(size_t)node * 64 + s * 8 + f]);
  } else {
    float2v o;
    o.x = o0;
    o.y = o1;
    __builtin_nontemporal_store(o, (float2v*)((float*)outp + (size_t)node * 128 + fb));
  }
}

// ============ launch ============
extern "C" void kernel_launch(void* const* d_in, const int* in_sizes, int n_in,
                              void* d_out, int out_size, void* d_ws, size_t ws_size,
                              hipStream_t stream) {
  const float* x = (const float*)d_in[0];
  const int* senders = (const int*)d_in[1];
  const int* recv = (const int*)d_in[2];
  const float* ev = (const float*)d_in[3];
  const float* W1 = (const float*)d_in[4];
  const float* b1 = (const float*)d_in[5];
  const float* W2 = (const float*)d_in[6];
  const float* b2 = (const float*)d_in[7];
  float* out = (float*)d_out;

  char* ws = (char*)d_ws;
  uint16_t* suppB = (uint16_t*)ws;            // 25,600,000 B  bf16 support table
  uint32_t* csr4 = (uint32_t*)(ws + 25600000);// 12,800,000 B  4B-record CSR
  char* bufB = ws + 38400000;                 // 25,600,000 B  pass1 buf, later h1 bf16
  int* offs = (int*)(ws + 64000000);          // 400,000 B
  int* counts = (int*)(ws + 64400000);        // 400,000 B
  int* bcount = (int*)(ws + 64800000);        // S1_NB ints
  int* bcursor = (int*)(ws + 64801600);       // S1_NB ints
  int* boffs = (int*)(ws + 64803200);         // S1_NB+1 ints
  uint16_t* wT = (uint16_t*)(ws + 64804800);  // 65,536 B  (end ~64.9 MB)

  (void)hipMemsetAsync(bcount, 0, S1_NB * sizeof(int), stream);
  k_bhist<<<256, 256, 0, stream>>>(recv, bcount);
  k_bscan<<<1, 512, 0, stream>>>(bcount, boffs, bcursor);
  k_sort1<<<S1_GRID, S1_T, 0, stream>>>(senders, recv, ev, bcursor, (uint2*)bufB);
  k_pass2<<<S1_NB, 256, 0, stream>>>((const uint2*)bufB, boffs, offs, counts, csr4);
  k_wprep<<<2, 256, 0, stream>>>(W1, W2, wT);

  // layer 1
  k_gemm<true><<<(NNODES + 63) / 64, 256, 0, stream>>>(x, wT, suppB);
  k_spmm<true><<<8 * (NNODES / 32), 256, 0, stream>>>(suppB, csr4, offs, counts, b1, bufB);
  // layer 2
  k_gemm<false><<<(NNODES + 63) / 64, 256, 0, stream>>>(bufB, wT + 16384, suppB);
  k_spmm<false><<<8 * (NNODES / 32), 256, 0, stream>>>(suppB, csr4, offs, counts, b2, out);
}